// Round 3
// baseline (523.287 us; speedup 1.0000x reference)
//
#include <hip/hip_runtime.h>

#define VOCABN 100
#define EMBN 10
#define UNITSN 32
#define DENSEN 25
#define BATCHN 4096
#define SEQN 512
#define G3 96  // 3*UNITS

// sigmoid(x) = 1/(1+e^-x);  e^-x = 2^(-x*log2 e)
__device__ __forceinline__ float fast_sigmoid(float x) {
    float e = __builtin_amdgcn_exp2f(x * -1.4426950408889634f);
    return __builtin_amdgcn_rcpf(1.0f + e);
}
// tanh(x) = 2*sigmoid(2x) - 1
__device__ __forceinline__ float fast_tanh(float x) {
    float e = __builtin_amdgcn_exp2f(x * -2.8853900817779268f);
    float s = __builtin_amdgcn_rcpf(1.0f + e);
    return 2.0f * s - 1.0f;
}

// Mapping: one batch per 64-lane wave. lane = (k, jj): k = lane>>5 picks the
// h-slice [16k, 16k+16); jj = lane&31 picks the gate/dense column. Each lane
// computes 16-term partial dots for its column's gate triple (48 FMA) plus a
// 16-term dense partial (16 FMA); partials are combined across halves with
// one __shfl_xor(.,32) per accumulator. Per-lane weight slice = 64 floats ->
// register-resident under the 128-VGPR cap. h is re-broadcast each step via
// a 32-float LDS row (in-wave DS ordering, no barrier needed).
__global__ __launch_bounds__(256, 4) void gru_fused_kernel(
    const int* __restrict__ inputs,
    const float* __restrict__ emb,
    const float* __restrict__ kern,
    const float* __restrict__ reck,
    const float* __restrict__ bias,
    const float* __restrict__ dw,
    const float* __restrict__ dbias,
    float* __restrict__ out)
{
    __shared__ float embP[VOCABN * G3];   // projected emb + b0 (+ b1 for z,r cols)
    __shared__ float hbuf[4][UNITSN];     // per-wave hidden-state broadcast row
    __shared__ int   idxb[4][64];         // staged token indices (64-step tiles)

    const int tid = threadIdx.x;

    // embP[v][n] = bias0[n] + (n<64 ? bias1[n] : 0) + sum_k emb[v,k]*kernel[k,n]
    // (recurrent bias for z,r folds in; hh's recurrent bias stays inside r*(.))
    for (int e = tid; e < VOCABN * G3; e += 256) {
        const int v = e / G3;
        const int n = e - v * G3;
        float a = bias[n] + ((n < 64) ? bias[G3 + n] : 0.0f);
        #pragma unroll
        for (int q = 0; q < EMBN; ++q)
            a = fmaf(emb[v * EMBN + q], kern[q * G3 + n], a);
        embP[e] = a;
    }
    __syncthreads();

    const int lane = tid & 63;
    const int wv   = tid >> 6;        // wave in block = batch row: 0..3
    const int k    = lane >> 5;       // half: h-slice selector
    const int jj   = lane & 31;       // gate/dense column
    const int u0   = k * 16;          // h-slice start
    const int batch = blockIdx.x * 4 + wv;

    // Register-resident weight slices: 64 floats/lane
    float wz[16], wr[16], wh[16], wd[16];
    #pragma unroll
    for (int i = 0; i < 16; ++i) {
        const int u = u0 + i;
        wz[i] = reck[u * G3 + jj];
        wr[i] = reck[u * G3 + 32 + jj];
        wh[i] = reck[u * G3 + 64 + jj];
        wd[i] = (jj < DENSEN) ? dw[u * DENSEN + jj] : 0.0f;
    }
    // hh recurrent bias: init lower-half partial only (avoid double count)
    const float rbh = k ? 0.0f : bias[G3 + 64 + jj];
    const float dbj = (k == 0 && jj < DENSEN) ? dbias[jj] : 0.0f;

    const int* __restrict__ inrow  = inputs + (size_t)batch * SEQN;
    float* __restrict__     outrow = out + (size_t)batch * (size_t)(SEQN * DENSEN);

    float h[16];
    #pragma unroll
    for (int i = 0; i < 16; ++i) h[i] = 0.0f;
    float hj = 0.0f;  // this lane's own unit value

    for (int t0 = 0; t0 < SEQN; t0 += 64) {
        idxb[wv][lane] = inrow[t0 + lane];   // coalesced 256B per wave

        for (int tt = 0; tt < 64; ++tt) {
            const int t = t0 + tt;
            const int idx = idxb[wv][tt];            // wave-uniform broadcast
            const float* ep = embP + idx * G3;
            const float xz = ep[jj];
            const float xr = ep[32 + jj];
            const float xh = ep[64 + jj];

            float rz = 0.0f, rr = 0.0f, rh = rbh;
            #pragma unroll
            for (int i = 0; i < 16; ++i) {
                rz = fmaf(h[i], wz[i], rz);
                rr = fmaf(h[i], wr[i], rr);
                rh = fmaf(h[i], wh[i], rh);
            }
            rz += __shfl_xor(rz, 32);
            rr += __shfl_xor(rr, 32);
            rh += __shfl_xor(rh, 32);

            const float z  = fast_sigmoid(xz + rz);
            const float r  = fast_sigmoid(xr + rr);
            const float hh = fast_tanh(fmaf(r, rh, xh));
            hj = fmaf(z, hj - hh, hh);               // z*h + (1-z)*hh

            // broadcast h_new (both halves hold identical hj; lower half writes)
            if (k == 0) hbuf[wv][jj] = hj;
            #pragma unroll
            for (int q = 0; q < 4; ++q) {
                const float4 v4 = *reinterpret_cast<const float4*>(&hbuf[wv][u0 + q * 4]);
                h[q * 4 + 0] = v4.x;
                h[q * 4 + 1] = v4.y;
                h[q * 4 + 2] = v4.z;
                h[q * 4 + 3] = v4.w;
            }

            // fused dense + relu on h(t): 16-term partial + cross-half combine
            float acc = dbj;
            #pragma unroll
            for (int i = 0; i < 16; ++i)
                acc = fmaf(h[i], wd[i], acc);
            acc += __shfl_xor(acc, 32);
            if (k == 0 && jj < DENSEN)
                outrow[t * DENSEN + jj] = fmaxf(acc, 0.0f);
        }
    }
}

extern "C" void kernel_launch(void* const* d_in, const int* in_sizes, int n_in,
                              void* d_out, int out_size, void* d_ws, size_t ws_size,
                              hipStream_t stream) {
    const int*   inputs = (const int*)d_in[0];
    const float* emb    = (const float*)d_in[1];
    const float* kern   = (const float*)d_in[2];
    const float* reck   = (const float*)d_in[3];
    const float* bias   = (const float*)d_in[4];
    const float* dw     = (const float*)d_in[5];
    const float* dbias  = (const float*)d_in[6];
    float* out = (float*)d_out;

    dim3 grid(BATCHN / 4);
    dim3 block(256);
    hipLaunchKernelGGL(gru_fused_kernel, grid, block, 0, stream,
                       inputs, emb, kern, reck, bias, dw, dbias, out);
}

// Round 4
// 519.635 us; speedup vs baseline: 1.0070x; 1.0070x over previous
//
#include <hip/hip_runtime.h>

#define VOCABN 100
#define EMBN 10
#define UNITSN 32
#define DENSEN 25
#define BATCHN 4096
#define SEQN 512
#define G3 96  // 3*UNITS

// sigmoid(x) = 1/(1+e^-x);  e^-x = 2^(-x*log2 e)
__device__ __forceinline__ float fast_sigmoid(float x) {
    float e = __builtin_amdgcn_exp2f(x * -1.4426950408889634f);
    return __builtin_amdgcn_rcpf(1.0f + e);
}
// tanh(x) = 2*sigmoid(2x) - 1
__device__ __forceinline__ float fast_tanh(float x) {
    float e = __builtin_amdgcn_exp2f(x * -2.8853900817779268f);
    float s = __builtin_amdgcn_rcpf(1.0f + e);
    return 2.0f * s - 1.0f;
}

// Mapping: one batch per 64-lane wave. lane = (k, jj): k = lane>>5 picks the
// h-slice [16k, 16k+16); jj = lane&31 picks the gate/dense column. Each lane
// computes 16-term partial dots for its column's gate triple (48 FMA) plus a
// 16-term dense partial (16 FMA); partials combined across halves with one
// __shfl_xor(.,32) per accumulator.
//
// amdgpu_waves_per_eu(4,4): pin the backend's occupancy TARGET to 4 waves/EU
// (LDS already caps at 4 blocks/CU), so it stops rematerializing the weight
// loads to stay under the 8-wave 64-VGPR budget (round-3 counter evidence:
// VGPR_Count=52, 227 VALU instrs/step vs ~100 ideal). The asm pins below
// make reload-rematerialization illegal outright.
__global__ __launch_bounds__(256)
__attribute__((amdgpu_waves_per_eu(4, 4)))
void gru_fused_kernel(
    const int* __restrict__ inputs,
    const float* __restrict__ emb,
    const float* __restrict__ kern,
    const float* __restrict__ reck,
    const float* __restrict__ bias,
    const float* __restrict__ dw,
    const float* __restrict__ dbias,
    float* __restrict__ out)
{
    __shared__ float embP[VOCABN * G3];   // projected emb + b0 (+ b1 for z,r cols)
    __shared__ float hbuf[4][UNITSN];     // per-wave hidden-state broadcast row
    __shared__ int   idxb[4][64];         // staged token indices (64-step tiles)

    const int tid = threadIdx.x;

    // embP[v][n] = bias0[n] + (n<64 ? bias1[n] : 0) + sum_k emb[v,k]*kernel[k,n]
    // (recurrent bias for z,r folds in; hh's recurrent bias stays inside r*(.))
    for (int e = tid; e < VOCABN * G3; e += 256) {
        const int v = e / G3;
        const int n = e - v * G3;
        float a = bias[n] + ((n < 64) ? bias[G3 + n] : 0.0f);
        #pragma unroll
        for (int q = 0; q < EMBN; ++q)
            a = fmaf(emb[v * EMBN + q], kern[q * G3 + n], a);
        embP[e] = a;
    }
    __syncthreads();

    const int lane = tid & 63;
    const int wv   = tid >> 6;        // wave in block = batch row: 0..3
    const int k    = lane >> 5;       // half: h-slice selector
    const int jj   = lane & 31;       // gate/dense column
    const int u0   = k * 16;          // h-slice start
    const int batch = blockIdx.x * 4 + wv;

    // Register-resident weight slices: 64 floats/lane
    float wz[16], wr[16], wh[16], wd[16];
    #pragma unroll
    for (int i = 0; i < 16; ++i) {
        const int u = u0 + i;
        wz[i] = reck[u * G3 + jj];
        wr[i] = reck[u * G3 + 32 + jj];
        wh[i] = reck[u * G3 + 64 + jj];
        wd[i] = (jj < DENSEN) ? dw[u * DENSEN + jj] : 0.0f;
    }
    // Pin: redefine each value through an opaque asm so the backend cannot
    // rematerialize them via per-step reloads — they must stay in VGPRs.
    #pragma unroll
    for (int i = 0; i < 16; ++i) {
        asm volatile("" : "+v"(wz[i]), "+v"(wr[i]), "+v"(wh[i]), "+v"(wd[i]));
    }

    // hh recurrent bias: init lower-half partial only (avoid double count)
    const float rbh = k ? 0.0f : bias[G3 + 64 + jj];
    const float dbj = (k == 0 && jj < DENSEN) ? dbias[jj] : 0.0f;

    const int* __restrict__ inrow  = inputs + (size_t)batch * SEQN;
    float* __restrict__     outrow = out + (size_t)batch * (size_t)(SEQN * DENSEN);

    float h[16];
    #pragma unroll
    for (int i = 0; i < 16; ++i) h[i] = 0.0f;
    float hj = 0.0f;  // this lane's own unit value

    for (int t0 = 0; t0 < SEQN; t0 += 64) {
        idxb[wv][lane] = inrow[t0 + lane];   // coalesced 256B per wave

        for (int tt = 0; tt < 64; ++tt) {
            const int t = t0 + tt;
            const int idx = idxb[wv][tt];            // wave-uniform broadcast
            const float* ep = embP + idx * G3;
            const float xz = ep[jj];
            const float xr = ep[32 + jj];
            const float xh = ep[64 + jj];

            float rz = 0.0f, rr = 0.0f, rh = rbh;
            #pragma unroll
            for (int i = 0; i < 16; ++i) {
                rz = fmaf(h[i], wz[i], rz);
                rr = fmaf(h[i], wr[i], rr);
                rh = fmaf(h[i], wh[i], rh);
            }
            rz += __shfl_xor(rz, 32);
            rr += __shfl_xor(rr, 32);
            rh += __shfl_xor(rh, 32);

            const float z  = fast_sigmoid(xz + rz);
            const float r  = fast_sigmoid(xr + rr);
            const float hh = fast_tanh(fmaf(r, rh, xh));
            hj = fmaf(z, hj - hh, hh);               // z*h + (1-z)*hh

            // broadcast h_new (both halves hold identical hj; lower half writes)
            if (k == 0) hbuf[wv][jj] = hj;
            #pragma unroll
            for (int q = 0; q < 4; ++q) {
                const float4 v4 = *reinterpret_cast<const float4*>(&hbuf[wv][u0 + q * 4]);
                h[q * 4 + 0] = v4.x;
                h[q * 4 + 1] = v4.y;
                h[q * 4 + 2] = v4.z;
                h[q * 4 + 3] = v4.w;
            }

            // fused dense + relu on h(t): 16-term partial + cross-half combine
            float acc = dbj;
            #pragma unroll
            for (int i = 0; i < 16; ++i)
                acc = fmaf(h[i], wd[i], acc);
            acc += __shfl_xor(acc, 32);
            if (k == 0 && jj < DENSEN)
                outrow[t * DENSEN + jj] = fmaxf(acc, 0.0f);
        }
    }
}

extern "C" void kernel_launch(void* const* d_in, const int* in_sizes, int n_in,
                              void* d_out, int out_size, void* d_ws, size_t ws_size,
                              hipStream_t stream) {
    const int*   inputs = (const int*)d_in[0];
    const float* emb    = (const float*)d_in[1];
    const float* kern   = (const float*)d_in[2];
    const float* reck   = (const float*)d_in[3];
    const float* bias   = (const float*)d_in[4];
    const float* dw     = (const float*)d_in[5];
    const float* dbias  = (const float*)d_in[6];
    float* out = (float*)d_out;

    dim3 grid(BATCHN / 4);
    dim3 block(256);
    hipLaunchKernelGGL(gru_fused_kernel, grid, block, 0, stream,
                       inputs, emb, kern, reck, bias, dw, dbias, out);
}

// Round 5
// 507.552 us; speedup vs baseline: 1.0310x; 1.0238x over previous
//
#include <hip/hip_runtime.h>

#define VOCABN 100
#define EMBN 10
#define UNITSN 32
#define DENSEN 25
#define BATCHN 4096
#define SEQN 512
#define G3 96  // 3*UNITS

typedef _Float16 half2v __attribute__((ext_vector_type(2)));

// sigmoid(x) = 1/(1+e^-x);  e^-x = 2^(-x*log2 e)
__device__ __forceinline__ float fast_sigmoid(float x) {
    float e = __builtin_amdgcn_exp2f(x * -1.4426950408889634f);
    return __builtin_amdgcn_rcpf(1.0f + e);
}
// tanh(x) = 2*sigmoid(2x) - 1
__device__ __forceinline__ float fast_tanh(float x) {
    float e = __builtin_amdgcn_exp2f(x * -2.8853900817779268f);
    float s = __builtin_amdgcn_rcpf(1.0f + e);
    return 2.0f * s - 1.0f;
}

// Mapping: one batch per 64-lane wave. lane = (k, jj): k = lane>>5 picks the
// h-slice [16k,16k+16); jj = lane&31 picks the gate/dense column. Each lane
// computes 16-term partial dots via 8x v_dot2_f32_f16 per accumulator
// (f16 inputs, f32 accumulate); halves combined with one __shfl_xor(.,32).
//
// Round-4 evidence: 64 f32 weight regs/lane blew the allocator's 64-VGPR
// budget -> AGPR copies (~130 extra VALU instr/step, VGPR_Count=52).
// Fix: f16-packed weights (32 regs) + f16 h broadcast (8 regs) fit the
// budget AND halve the dot-product instruction stream. The recurrence
// carry hj stays f32, so f16 quantization never compounds across steps.
__global__ __launch_bounds__(256)
__attribute__((amdgpu_waves_per_eu(4, 4)))
void gru_fused_kernel(
    const int* __restrict__ inputs,
    const float* __restrict__ emb,
    const float* __restrict__ kern,
    const float* __restrict__ reck,
    const float* __restrict__ bias,
    const float* __restrict__ dw,
    const float* __restrict__ dbias,
    float* __restrict__ out)
{
    __shared__ float embP[VOCABN * G3];            // projected emb + b0 (+ b1 for z,r)
    __shared__ __align__(16) _Float16 hbuf[4][UNITSN]; // per-wave f16 hidden broadcast
    __shared__ int idxb[4][64];                    // staged token indices

    const int tid = threadIdx.x;

    // embP[v][n] = bias0[n] + (n<64 ? bias1[n] : 0) + sum_k emb[v,k]*kernel[k,n]
    for (int e = tid; e < VOCABN * G3; e += 256) {
        const int v = e / G3;
        const int n = e - v * G3;
        float a = bias[n] + ((n < 64) ? bias[G3 + n] : 0.0f);
        #pragma unroll
        for (int q = 0; q < EMBN; ++q)
            a = fmaf(emb[v * EMBN + q], kern[q * G3 + n], a);
        embP[e] = a;
    }
    __syncthreads();

    const int lane = tid & 63;
    const int wv   = tid >> 6;        // wave in block = batch row: 0..3
    const int k    = lane >> 5;       // half: h-slice selector
    const int jj   = lane & 31;       // gate/dense column
    const int u0   = k * 16;          // h-slice start
    const int batch = blockIdx.x * 4 + wv;

    // f16-packed register-resident weight slices: 32 dword regs/lane
    half2v wz2[8], wr2[8], wh2[8], wd2[8];
    #pragma unroll
    for (int i = 0; i < 8; ++i) {
        const int u = u0 + 2 * i;
        wz2[i] = half2v{(_Float16)reck[u * G3 + jj],       (_Float16)reck[(u + 1) * G3 + jj]};
        wr2[i] = half2v{(_Float16)reck[u * G3 + 32 + jj],  (_Float16)reck[(u + 1) * G3 + 32 + jj]};
        wh2[i] = half2v{(_Float16)reck[u * G3 + 64 + jj],  (_Float16)reck[(u + 1) * G3 + 64 + jj]};
        const float d0 = (jj < DENSEN) ? dw[u * DENSEN + jj] : 0.0f;
        const float d1 = (jj < DENSEN) ? dw[(u + 1) * DENSEN + jj] : 0.0f;
        wd2[i] = half2v{(_Float16)d0, (_Float16)d1};
    }
    // Pin packed weights so the backend can't rematerialize via reloads.
    #pragma unroll
    for (int i = 0; i < 8; ++i) {
        asm volatile("" : "+v"(wz2[i]), "+v"(wr2[i]), "+v"(wh2[i]), "+v"(wd2[i]));
    }

    // hh recurrent bias: init lower-half partial only (avoid double count)
    const float rbh = k ? 0.0f : bias[G3 + 64 + jj];
    const float dbj = (k == 0 && jj < DENSEN) ? dbias[jj] : 0.0f;

    const int* __restrict__ inrow  = inputs + (size_t)batch * SEQN;
    float* __restrict__     outrow = out + (size_t)batch * (size_t)(SEQN * DENSEN);

    half2v h2[8];
    #pragma unroll
    for (int i = 0; i < 8; ++i) h2[i] = half2v{(_Float16)0.0f, (_Float16)0.0f};
    float hj = 0.0f;  // f32 recurrence carry (own unit)

    for (int t0 = 0; t0 < SEQN; t0 += 64) {
        idxb[wv][lane] = inrow[t0 + lane];   // coalesced 256B per wave

        for (int tt = 0; tt < 64; ++tt) {
            const int t = t0 + tt;
            const int idx = idxb[wv][tt];            // wave-uniform broadcast
            const float* ep = embP + idx * G3;
            const float xz = ep[jj];
            const float xr = ep[32 + jj];
            const float xh = ep[64 + jj];

            float rz = 0.0f, rr = 0.0f, rh = rbh;
            #pragma unroll
            for (int i = 0; i < 8; ++i) {
                rz = __builtin_amdgcn_fdot2(h2[i], wz2[i], rz, false);
                rr = __builtin_amdgcn_fdot2(h2[i], wr2[i], rr, false);
                rh = __builtin_amdgcn_fdot2(h2[i], wh2[i], rh, false);
            }
            rz += __shfl_xor(rz, 32);
            rr += __shfl_xor(rr, 32);
            rh += __shfl_xor(rh, 32);

            const float z  = fast_sigmoid(xz + rz);
            const float r  = fast_sigmoid(xr + rr);
            const float hh = fast_tanh(fmaf(r, rh, xh));
            hj = fmaf(z, hj - hh, hh);               // z*h + (1-z)*hh

            // broadcast h_new as f16 (lower half writes its own unit)
            if (k == 0) hbuf[wv][jj] = (_Float16)hj;
            // refresh this lane's 16-value slice: 2x 16B LDS reads
            *reinterpret_cast<float4*>(&h2[0]) =
                *reinterpret_cast<const float4*>(&hbuf[wv][u0]);
            *reinterpret_cast<float4*>(&h2[4]) =
                *reinterpret_cast<const float4*>(&hbuf[wv][u0 + 8]);

            // fused dense + relu on h(t): 8x dot2 partial + cross-half combine
            float acc = dbj;
            #pragma unroll
            for (int i = 0; i < 8; ++i)
                acc = __builtin_amdgcn_fdot2(h2[i], wd2[i], acc, false);
            acc += __shfl_xor(acc, 32);
            if (k == 0 && jj < DENSEN)
                outrow[t * DENSEN + jj] = fmaxf(acc, 0.0f);
        }
    }
}

extern "C" void kernel_launch(void* const* d_in, const int* in_sizes, int n_in,
                              void* d_out, int out_size, void* d_ws, size_t ws_size,
                              hipStream_t stream) {
    const int*   inputs = (const int*)d_in[0];
    const float* emb    = (const float*)d_in[1];
    const float* kern   = (const float*)d_in[2];
    const float* reck   = (const float*)d_in[3];
    const float* bias   = (const float*)d_in[4];
    const float* dw     = (const float*)d_in[5];
    const float* dbias  = (const float*)d_in[6];
    float* out = (float*)d_out;

    dim3 grid(BATCHN / 4);
    dim3 block(256);
    hipLaunchKernelGGL(gru_fused_kernel, grid, block, 0, stream,
                       inputs, emb, kern, reck, bias, dw, dbias, out);
}